// Round 1
// baseline (2718.731 us; speedup 1.0000x reference)
//
#include <hip/hip_runtime.h>
#include <hip/hip_bf16.h>
#include <math.h>

#define B_DIM 8
#define C_DIM 256
#define N_DIM 2048
#define CQ 64

#define TM 64
#define TN 64
#define TK 16

// pos[b,c,n] = sum_i w[c,i]*xyz[b,n,i]
__global__ void pos_kernel(const float* __restrict__ w, const float* __restrict__ xyz,
                           float* __restrict__ pos) {
  int n = blockIdx.x * blockDim.x + threadIdx.x;
  int c = blockIdx.y;
  int b = blockIdx.z;
  const float* xp = xyz + ((long long)b * N_DIM + n) * 3;
  pos[((long long)b * C_DIM + c) * N_DIM + n] =
      w[c * 3 + 0] * xp[0] + w[c * 3 + 1] * xp[1] + w[c * 3 + 2] * xp[2];
}

// Y[b,m,n] = epi( sum_k W[m,k] * (X[b,k,n] + Xadd[b,k,n]) )
// epi: +bias[m]; optional BN(scale/shift from g,b,m,v)+ReLU; optional +Res[b,m,n]
__global__ void gemm_wx(const float* __restrict__ W,
                        const float* __restrict__ X, long long sxB,
                        const float* __restrict__ Xadd, long long saB,
                        const float* __restrict__ bias,
                        const float* __restrict__ bng, const float* __restrict__ bnb,
                        const float* __restrict__ bnm, const float* __restrict__ bnv,
                        const float* __restrict__ Res, long long srB,
                        float* __restrict__ Y, long long syB,
                        int M, int K) {
  const int N = N_DIM;
  int b = blockIdx.z;
  int m0 = blockIdx.y * TM;
  int n0 = blockIdx.x * TN;
  int t = threadIdx.x;
  int tx = t & 15, ty = t >> 4;
  __shared__ float As[TK][TM + 1];
  __shared__ float Bs[TK][TN];
  float acc[4][4] = {};
  const float* Xb = X + (long long)b * sxB;
  const float* Ab = Xadd ? Xadd + (long long)b * saB : nullptr;
  for (int k0 = 0; k0 < K; k0 += TK) {
#pragma unroll
    for (int v = 0; v < 4; v++) {
      int l = t * 4 + v;
      int i = l >> 4, k = l & 15;
      As[k][i] = W[(long long)(m0 + i) * K + k0 + k];
    }
#pragma unroll
    for (int v = 0; v < 4; v++) {
      int l = t * 4 + v;
      int k = l >> 6, j = l & 63;
      float x = Xb[(long long)(k0 + k) * N + n0 + j];
      if (Ab) x += Ab[(long long)(k0 + k) * N + n0 + j];
      Bs[k][j] = x;
    }
    __syncthreads();
#pragma unroll
    for (int k = 0; k < TK; k++) {
      float a[4], bb[4];
#pragma unroll
      for (int ii = 0; ii < 4; ii++) a[ii] = As[k][ty * 4 + ii];
#pragma unroll
      for (int jj = 0; jj < 4; jj++) bb[jj] = Bs[k][tx * 4 + jj];
#pragma unroll
      for (int ii = 0; ii < 4; ii++)
#pragma unroll
        for (int jj = 0; jj < 4; jj++)
          acc[ii][jj] = fmaf(a[ii], bb[jj], acc[ii][jj]);
    }
    __syncthreads();
  }
#pragma unroll
  for (int ii = 0; ii < 4; ii++) {
    int m = m0 + ty * 4 + ii;
    float sh = bias ? bias[m] : 0.f;
    bool dobn = (bng != nullptr);
    float bnsc = 0.f, bnsh = 0.f;
    if (dobn) {
      bnsc = bng[m] * rsqrtf(bnv[m] + 1e-5f);
      bnsh = bnb[m] - bnm[m] * bnsc;
    }
#pragma unroll
    for (int jj = 0; jj < 4; jj++) {
      int n = n0 + tx * 4 + jj;
      float v = acc[ii][jj] + sh;
      if (dobn) v = fmaxf(v * bnsc + bnsh, 0.f);
      if (Res) v += Res[(long long)b * srB + (long long)m * N + n];
      Y[(long long)b * syB + (long long)m * N + n] = v;
    }
  }
}

// E[b,r,c] = sum_d q[b,d,r]*q[b,d,c], q: [B, CQ, N]
__global__ void energy_kernel(const float* __restrict__ q, float* __restrict__ E) {
  const int N = N_DIM;
  int b = blockIdx.z;
  int r0 = blockIdx.y * TM;
  int c0 = blockIdx.x * TN;
  int t = threadIdx.x;
  int tx = t & 15, ty = t >> 4;
  __shared__ float As[TK][TM];
  __shared__ float Bs[TK][TN];
  float acc[4][4] = {};
  const float* qb = q + (long long)b * CQ * N;
  for (int k0 = 0; k0 < CQ; k0 += TK) {
#pragma unroll
    for (int v = 0; v < 4; v++) {
      int l = t * 4 + v;
      int k = l >> 6, j = l & 63;
      As[k][j] = qb[(long long)(k0 + k) * N + r0 + j];
      Bs[k][j] = qb[(long long)(k0 + k) * N + c0 + j];
    }
    __syncthreads();
#pragma unroll
    for (int k = 0; k < TK; k++) {
      float a[4], bb[4];
#pragma unroll
      for (int ii = 0; ii < 4; ii++) a[ii] = As[k][ty * 4 + ii];
#pragma unroll
      for (int jj = 0; jj < 4; jj++) bb[jj] = Bs[k][tx * 4 + jj];
#pragma unroll
      for (int ii = 0; ii < 4; ii++)
#pragma unroll
        for (int jj = 0; jj < 4; jj++)
          acc[ii][jj] = fmaf(a[ii], bb[jj], acc[ii][jj]);
    }
    __syncthreads();
  }
  long long base = (long long)b * N * N;
#pragma unroll
  for (int ii = 0; ii < 4; ii++)
#pragma unroll
    for (int jj = 0; jj < 4; jj++)
      E[base + (long long)(r0 + ty * 4 + ii) * N + c0 + tx * 4 + jj] = acc[ii][jj];
}

// row softmax in place; one block (256 thr) per row of length 2048
__global__ void softmax_kernel(float* __restrict__ E) {
  const int N = N_DIM;
  long long row = blockIdx.x;
  float* p = E + row * N;
  int t = threadIdx.x;
  float v[8];
#pragma unroll
  for (int i = 0; i < 8; i++) v[i] = p[t + i * 256];
  float m = v[0];
#pragma unroll
  for (int i = 1; i < 8; i++) m = fmaxf(m, v[i]);
  for (int o = 32; o > 0; o >>= 1) m = fmaxf(m, __shfl_down(m, o, 64));
  __shared__ float red[4];
  int wid = t >> 6, lane = t & 63;
  if (lane == 0) red[wid] = m;
  __syncthreads();
  m = fmaxf(fmaxf(red[0], red[1]), fmaxf(red[2], red[3]));
  __syncthreads();
  float s = 0.f;
#pragma unroll
  for (int i = 0; i < 8; i++) {
    v[i] = __expf(v[i] - m);
    s += v[i];
  }
  for (int o = 32; o > 0; o >>= 1) s += __shfl_down(s, o, 64);
  if (lane == 0) red[wid] = s;
  __syncthreads();
  s = red[0] + red[1] + red[2] + red[3];
  float inv = 1.0f / s;
#pragma unroll
  for (int i = 0; i < 8; i++) p[t + i * 256] = v[i] * inv;
}

// cs[b,m] = sum_n att[b,n,m]
__global__ void colsum_kernel(const float* __restrict__ E, float* __restrict__ cs) {
  const int N = N_DIM;
  int t = threadIdx.x;
  int tx = t & 63, tz = t >> 6;
  int m = blockIdx.x * 64 + tx;
  int b = blockIdx.y;
  const float* p = E + (long long)b * N * N + m;
  float s = 0.f;
  for (int n = tz; n < N; n += 4) s += p[(long long)n * N];
  __shared__ float sm[4][64];
  sm[tz][tx] = s;
  __syncthreads();
  if (tz == 0) cs[(long long)b * N + m] = sm[0][tx] + sm[1][tx] + sm[2][tx] + sm[3][tx];
}

// D[b,c,n] = Hprev[b,c,n] - (sum_k val[b,c,k]*att[b,k,n]) / (1e-9 + cs[b,n])
__global__ void pv_kernel(const float* __restrict__ val, const float* __restrict__ att,
                          const float* __restrict__ cs,
                          const float* __restrict__ Hprev, long long shB,
                          float* __restrict__ D) {
  const int N = N_DIM;
  int b = blockIdx.z;
  int m0 = blockIdx.y * TM;
  int n0 = blockIdx.x * TN;
  int t = threadIdx.x;
  int tx = t & 15, ty = t >> 4;
  __shared__ float As[TK][TM + 1];
  __shared__ float Bs[TK][TN];
  float acc[4][4] = {};
  const float* vb = val + (long long)b * C_DIM * N;
  const float* ab = att + (long long)b * N * N;
  for (int k0 = 0; k0 < N; k0 += TK) {
#pragma unroll
    for (int v = 0; v < 4; v++) {
      int l = t * 4 + v;
      int i = l >> 4, k = l & 15;
      As[k][i] = vb[(long long)(m0 + i) * N + k0 + k];
    }
#pragma unroll
    for (int v = 0; v < 4; v++) {
      int l = t * 4 + v;
      int k = l >> 6, j = l & 63;
      Bs[k][j] = ab[(long long)(k0 + k) * N + n0 + j];
    }
    __syncthreads();
#pragma unroll
    for (int k = 0; k < TK; k++) {
      float a[4], bb[4];
#pragma unroll
      for (int ii = 0; ii < 4; ii++) a[ii] = As[k][ty * 4 + ii];
#pragma unroll
      for (int jj = 0; jj < 4; jj++) bb[jj] = Bs[k][tx * 4 + jj];
#pragma unroll
      for (int ii = 0; ii < 4; ii++)
#pragma unroll
        for (int jj = 0; jj < 4; jj++)
          acc[ii][jj] = fmaf(a[ii], bb[jj], acc[ii][jj]);
    }
    __syncthreads();
  }
#pragma unroll
  for (int ii = 0; ii < 4; ii++) {
    int c = m0 + ty * 4 + ii;
#pragma unroll
    for (int jj = 0; jj < 4; jj++) {
      int n = n0 + tx * 4 + jj;
      float denom = 1e-9f + cs[(long long)b * N + n];
      float xr = acc[ii][jj] / denom;
      D[(long long)b * C_DIM * N + (long long)c * N + n] =
          Hprev[(long long)b * shB + (long long)c * N + n] - xr;
    }
  }
}

extern "C" void kernel_launch(void* const* d_in, const int* in_sizes, int n_in,
                              void* d_out, int out_size, void* d_ws, size_t ws_size,
                              hipStream_t stream) {
  const float* x = (const float*)d_in[0];
  const float* xyz = (const float*)d_in[1];
  const float* conv1_w = (const float*)d_in[2];
  const float* convpos_w = (const float*)d_in[3];
  const float* bn1_g = (const float*)d_in[4];
  const float* bn1_b = (const float*)d_in[5];
  const float* bn1_m = (const float*)d_in[6];
  const float* bn1_v = (const float*)d_in[7];
  const float* Wqk = (const float*)d_in[8];   // [4,64,256]
  const float* Wv = (const float*)d_in[9];    // [4,256,256]
  const float* bv = (const float*)d_in[10];   // [4,256]
  const float* Wt = (const float*)d_in[11];   // [4,256,256]
  const float* bt = (const float*)d_in[12];   // [4,256]
  const float* bng = (const float*)d_in[13];
  const float* bnb = (const float*)d_in[14];
  const float* bnm = (const float*)d_in[15];
  const float* bnv = (const float*)d_in[16];
  float* out = (float*)d_out;

  const long long BCN = (long long)B_DIM * C_DIM * N_DIM;
  const long long CN = (long long)C_DIM * N_DIM;
  float* ws = (float*)d_ws;
  float* pos = ws;                                   // BCN
  float* h0 = pos + BCN;                             // BCN
  float* qbuf = h0 + BCN;                            // B*CQ*N
  float* valb = qbuf + (long long)B_DIM * CQ * N_DIM;  // BCN
  float* dbuf = valb + BCN;                          // BCN
  float* csum = dbuf + BCN;                          // B*N
  float* att = csum + (long long)B_DIM * N_DIM;      // B*N*N

  dim3 blk(256);

  pos_kernel<<<dim3(N_DIM / 256, C_DIM, B_DIM), blk, 0, stream>>>(convpos_w, xyz, pos);

  // h0 = relu(bn1(conv1_w @ x))
  gemm_wx<<<dim3(N_DIM / TN, C_DIM / TM, B_DIM), blk, 0, stream>>>(
      conv1_w, x, CN, nullptr, 0, nullptr,
      bn1_g, bn1_b, bn1_m, bn1_v, nullptr, 0, h0, CN, C_DIM, C_DIM);

  for (int i = 0; i < 4; i++) {
    const float* hp = (i == 0) ? h0 : out + (long long)(i - 1) * CN;
    long long shp = (i == 0) ? CN : 4 * CN;

    // q = Wqk_i @ (h + pos)
    gemm_wx<<<dim3(N_DIM / TN, CQ / TM, B_DIM), blk, 0, stream>>>(
        Wqk + (long long)i * CQ * C_DIM, hp, shp, pos, CN, nullptr,
        nullptr, nullptr, nullptr, nullptr, nullptr, 0,
        qbuf, (long long)CQ * N_DIM, CQ, C_DIM);

    // val = Wv_i @ (h + pos) + bv_i
    gemm_wx<<<dim3(N_DIM / TN, C_DIM / TM, B_DIM), blk, 0, stream>>>(
        Wv + (long long)i * C_DIM * C_DIM, hp, shp, pos, CN, bv + i * C_DIM,
        nullptr, nullptr, nullptr, nullptr, nullptr, 0,
        valb, CN, C_DIM, C_DIM);

    energy_kernel<<<dim3(N_DIM / TN, N_DIM / TM, B_DIM), blk, 0, stream>>>(qbuf, att);

    softmax_kernel<<<dim3(B_DIM * N_DIM), blk, 0, stream>>>(att);

    colsum_kernel<<<dim3(N_DIM / 64, B_DIM), blk, 0, stream>>>(att, csum);

    pv_kernel<<<dim3(N_DIM / TN, C_DIM / TM, B_DIM), blk, 0, stream>>>(
        valb, att, csum, hp, shp, dbuf);

    // out_i = h + relu(bn_i(Wt_i @ d + bt_i))
    gemm_wx<<<dim3(N_DIM / TN, C_DIM / TM, B_DIM), blk, 0, stream>>>(
        Wt + (long long)i * C_DIM * C_DIM, dbuf, CN, nullptr, 0, bt + i * C_DIM,
        bng + i * C_DIM, bnb + i * C_DIM, bnm + i * C_DIM, bnv + i * C_DIM,
        hp, shp, out + (long long)i * CN, 4 * CN, C_DIM, C_DIM);
  }
}